// Round 20
// baseline (65.844 us; speedup 1.0000x reference)
//
#include <hip/hip_runtime.h>
#include <math.h>

#define BATCH 4
#define SEQ   4096
#define EMB   1024
#define HDIM  64
#define NSPLIT 8

typedef __attribute__((ext_vector_type(8))) short bf16x8;
typedef __attribute__((ext_vector_type(4))) float f32x4;
typedef __attribute__((ext_vector_type(4))) unsigned int u32x4;

#define MFMA16(a, b, c) __builtin_amdgcn_mfma_f32_16x16x32_bf16(a, b, c, 0, 0, 0)

__device__ __forceinline__ unsigned short f2bf(float f) {
  unsigned int u = __float_as_uint(f);
  u = (u + 0x7FFFu + ((u >> 16) & 1u)) >> 16;   // RNE
  return (unsigned short)u;
}

__device__ __forceinline__ float fexp2(float x) {  // 2^x, hw v_exp_f32
  float r;
  asm("v_exp_f32 %0, %1" : "=v"(r) : "v"(x));
  return r;
}

// ---- W pre-transpose: W[1024][64] f32 x3 -> Wt[192][1024] bf16 --------------
__global__ __launch_bounds__(256) void wt_kernel(
    const float* __restrict__ Wq, const float* __restrict__ Wk,
    const float* __restrict__ Wv, unsigned short* __restrict__ wt) {
  __shared__ float tile[64][65];
  const int bid = blockIdx.x;           // 48 = 3 matrices x 16 k-tiles
  const int m = bid >> 4, kt = bid & 15;
  const float* W = (m == 0) ? Wq : (m == 1) ? Wk : Wv;
  const int tid = threadIdx.x;
  {
    const int r = tid >> 2, c4 = tid & 3;
    const float* src = W + (size_t)(kt * 64 + r) * 64 + c4 * 16;
#pragma unroll
    for (int j = 0; j < 4; ++j) {
      float4 a = *(const float4*)(src + j * 4);
      tile[r][c4 * 16 + j * 4 + 0] = a.x;
      tile[r][c4 * 16 + j * 4 + 1] = a.y;
      tile[r][c4 * 16 + j * 4 + 2] = a.z;
      tile[r][c4 * 16 + j * 4 + 3] = a.w;
    }
  }
  __syncthreads();
  {
    const int col = tid >> 2, kq = tid & 3;
    unsigned short o[16];
#pragma unroll
    for (int j = 0; j < 16; ++j) o[j] = f2bf(tile[kq * 16 + j][col]);
    unsigned short* dst = wt + (size_t)(m * 64 + col) * 1024 + kt * 64 + kq * 16;
    *(bf16x8*)(dst)     = *(bf16x8*)&o[0];
    *(bf16x8*)(dst + 8) = *(bf16x8*)&o[8];
  }
}

// ---------------- QKV projection via MFMA: 64-row M-tile, 8 waves (r18) -----
__global__ __launch_bounds__(512) void qkv_mfma_kernel(
    const float* __restrict__ x, const unsigned short* __restrict__ wt,
    unsigned short* __restrict__ qb, unsigned short* __restrict__ kb,
    unsigned short* __restrict__ vt) {
  __shared__ __align__(16) unsigned short xs[64 * 64];
  __shared__ __align__(16) unsigned short ws[192 * 64];
  const int tid  = threadIdx.x;
  const int lane = tid & 63, wid = tid >> 6;
  const int g = lane >> 4, p = lane & 15;
  const int mt = wid >> 2, wq = wid & 3;
  const size_t row0 = (size_t)blockIdx.x * 64;

  const int sr = tid >> 3, sc = tid & 7;
  const float* xp = x + (row0 + sr) * EMB + sc * 8;

  f32x4 acc[2][3];
#pragma unroll
  for (int rt = 0; rt < 2; ++rt)
#pragma unroll
    for (int ct = 0; ct < 3; ++ct) acc[rt][ct] = (f32x4){0.f, 0.f, 0.f, 0.f};

  float4 rx[2];
  bf16x8 rw[3];
#pragma unroll
  for (int j = 0; j < 2; ++j) rx[j] = *(const float4*)(xp + j * 4);
#pragma unroll
  for (int it = 0; it < 3; ++it) {
    int i = tid + it * 512, col = i >> 3, cc = i & 7;
    rw[it] = *(const bf16x8*)(wt + (size_t)col * 1024 + cc * 8);
  }

  for (int kc = 0; kc < 16; ++kc) {
    __syncthreads();
#pragma unroll
    for (int j = 0; j < 2; ++j) {
      ushort4 h;
      h.x = f2bf(rx[j].x); h.y = f2bf(rx[j].y);
      h.z = f2bf(rx[j].z); h.w = f2bf(rx[j].w);
      *(ushort4*)((char*)xs + ((sr * 128 + sc * 16 + j * 8) ^ ((sr & 7) << 4))) = h;
    }
#pragma unroll
    for (int it = 0; it < 3; ++it) {
      int i = tid + it * 512, col = i >> 3, cc = i & 7;
      *(bf16x8*)((char*)ws + ((col * 128 + cc * 16) ^ ((col & 7) << 4))) = rw[it];
    }
    if (kc < 15) {
      const float* xpn = xp + (kc + 1) * 64;
#pragma unroll
      for (int j = 0; j < 2; ++j) rx[j] = *(const float4*)(xpn + j * 4);
#pragma unroll
      for (int it = 0; it < 3; ++it) {
        int i = tid + it * 512, col = i >> 3, cc = i & 7;
        rw[it] = *(const bf16x8*)(wt + (size_t)col * 1024 + (kc + 1) * 64 + cc * 8);
      }
    }
    __syncthreads();
#pragma unroll
    for (int ks = 0; ks < 2; ++ks) {
      bf16x8 af[2];
#pragma unroll
      for (int rt = 0; rt < 2; ++rt) {
        int row = mt * 32 + rt * 16 + p;
        af[rt] = *(const bf16x8*)((char*)xs +
                 ((row * 128 + ks * 64 + g * 16) ^ ((row & 7) << 4)));
      }
#pragma unroll
      for (int ct = 0; ct < 3; ++ct) {
        int col = wq * 48 + ct * 16 + p;
        bf16x8 bfr = *(const bf16x8*)((char*)ws +
                     ((col * 128 + ks * 64 + g * 16) ^ ((col & 7) << 4)));
#pragma unroll
        for (int rt = 0; rt < 2; ++rt)
          acc[rt][ct] = MFMA16(af[rt], bfr, acc[rt][ct]);
      }
    }
  }

  const int b     = (int)(row0 >> 12);
  const int tbase = (int)(row0 & 4095);
  unsigned short* vtb = vt + (((size_t)b * 64 + (tbase >> 6)) * 64) * 64;
#pragma unroll
  for (int rt = 0; rt < 2; ++rt)
#pragma unroll
    for (int ct = 0; ct < 3; ++ct) {
      const int c0  = wq * 48 + ct * 16;
      const int mtx = c0 >> 6;
      const int col = (c0 & 63) + p;
#pragma unroll
      for (int r = 0; r < 4; ++r) {
        const int row = mt * 32 + rt * 16 + 4 * g + r;
        const float vf = acc[rt][ct][r];
        if (mtx == 0)      qb[(row0 + row) * HDIM + col] = f2bf(vf * 0.0450843714f);
        else if (mtx == 1) kb[(row0 + row) * HDIM + col] = f2bf(vf);
        else               vtb[(size_t)col * 64 + row]   = f2bf(vf);
      }
    }
}

// ---- one 64-key tile from swizzled LDS; cvt_pk + word-shuffle transpose ----
__device__ __forceinline__ void tile_body_lds(
    const unsigned short* __restrict__ sKb, const unsigned short* __restrict__ sVb,
    int qrel, bool diag,
    const bf16x8& qf0, const bf16x8& qf1,
    int p, int g, int cA0, int cA1, int srcA, int srcB, bool hi,
    float& m, float& l, f32x4 (&o)[4]) {
  f32x4 sc4[4];
#pragma unroll
  for (int t = 0; t < 4; ++t) {
    const int row = 16 * t + p;
    bf16x8 a0 = *(const bf16x8*)((const char*)sKb + row * 128 + cA0);
    bf16x8 a1 = *(const bf16x8*)((const char*)sKb + row * 128 + cA1);
    f32x4 a = (f32x4){0.f, 0.f, 0.f, 0.f};
    a = MFMA16(a0, qf0, a);
    a = MFMA16(a1, qf1, a);
    sc4[t] = a;
  }
  if (diag) {
#pragma unroll
    for (int t = 0; t < 4; ++t)
#pragma unroll
      for (int r = 0; r < 4; ++r)
        if (16 * t + 4 * g + r > qrel) sc4[t][r] = -1e30f;
  }
  float tm = -3e38f;
#pragma unroll
  for (int t = 0; t < 4; ++t)
#pragma unroll
    for (int r = 0; r < 4; ++r) tm = fmaxf(tm, sc4[t][r]);
  tm = fmaxf(tm, __shfl_xor(tm, 16));
  tm = fmaxf(tm, __shfl_xor(tm, 32));
  if (__any(tm > m + 11.5f)) {               // defer-max (T13)
    float mn = fmaxf(m, tm);
    float c = fexp2(m - mn);
    l *= c;
#pragma unroll
    for (int mi = 0; mi < 4; ++mi) o[mi] *= c;
    m = mn;
  }
  float psum = 0.f;
#pragma unroll
  for (int t = 0; t < 4; ++t)
#pragma unroll
    for (int r = 0; r < 4; ++r) {
      float pv = fexp2(sc4[t][r] - m);
      sc4[t][r] = pv;
      psum += pv;
    }
  l += psum;
  unsigned int pk[4][2];
#pragma unroll
  for (int t = 0; t < 4; ++t) {
    asm("v_cvt_pk_bf16_f32 %0, %1, %2"
        : "=v"(pk[t][0]) : "v"(sc4[t][0]), "v"(sc4[t][1]));
    asm("v_cvt_pk_bf16_f32 %0, %1, %2"
        : "=v"(pk[t][1]) : "v"(sc4[t][2]), "v"(sc4[t][3]));
  }
  u32x4 wb0, wb1;
#pragma unroll
  for (int h2 = 0; h2 < 2; ++h2) {
    const int src = h2 ? srcB : srcA;
    unsigned c0 = (unsigned)__shfl((int)pk[0][0], src);
    unsigned c1 = (unsigned)__shfl((int)pk[1][0], src);
    wb0[2 * h2 + 0] = hi ? c1 : c0;
    unsigned d0 = (unsigned)__shfl((int)pk[0][1], src);
    unsigned d1 = (unsigned)__shfl((int)pk[1][1], src);
    wb0[2 * h2 + 1] = hi ? d1 : d0;
    unsigned e0 = (unsigned)__shfl((int)pk[2][0], src);
    unsigned e1 = (unsigned)__shfl((int)pk[3][0], src);
    wb1[2 * h2 + 0] = hi ? e1 : e0;
    unsigned f0 = (unsigned)__shfl((int)pk[2][1], src);
    unsigned f1 = (unsigned)__shfl((int)pk[3][1], src);
    wb1[2 * h2 + 1] = hi ? f1 : f0;
  }
  bf16x8 b0 = __builtin_bit_cast(bf16x8, wb0);
  bf16x8 b1 = __builtin_bit_cast(bf16x8, wb1);
#pragma unroll
  for (int mi = 0; mi < 4; ++mi) {
    const int rowv = 16 * mi + p;
    bf16x8 va0 = *(const bf16x8*)((const char*)sVb + rowv * 128 + cA0);
    bf16x8 va1 = *(const bf16x8*)((const char*)sVb + rowv * 128 + cA1);
    o[mi] = MFMA16(va0, b0, o[mi]);
    o[mi] = MFMA16(va1, b1, o[mi]);
  }
}

// pair (j, 31-j) of 128-row q-blocks; nA=2j+2, nB=64-2j, 66 items total.
__device__ __forceinline__ void item_map128(int g_it, int nA, int nB,
                                            int& kt, bool& isA, bool& diag) {
  if (g_it < nA) { isA = true;  kt = g_it;      diag = (kt >= nA - 2); }
  else           { isA = false; kt = g_it - nA; diag = (kt >= nB - 2); }
}

// ---- flash attention stage 1: 128-row Q pairs, NSPLIT=8 --------------------
// Grid 512 x 512thr = 2 blocks/CU = 16 waves/CU (4 waves/SIMD latency hiding).
// Item list partitioned across sp-blocks -> staging traffic unchanged (69MB).
__global__ __launch_bounds__(512) void attn_partial_kernel(
    const unsigned short* __restrict__ qb, const unsigned short* __restrict__ kbm,
    const unsigned short* __restrict__ vt, float* __restrict__ pw) {
  __shared__ __align__(16) unsigned short sK[2][4096];
  __shared__ __align__(16) unsigned short sV[2][4096];
  const int tid = threadIdx.x;
  const int wid = tid >> 6, lane = tid & 63;     // wid 0..7
  const int g = lane >> 4, p = lane & 15;
  const int bid = blockIdx.x;
  const int sp = bid & 7, j = (bid >> 3) & 15, b = bid >> 7;
  const int jB = 31 - j;
  const int nA = 2 * j + 2, nB = 64 - 2 * j;     // nA+nB == 66
  const int tq0A = j * 128 + 16 * wid;
  const int tq0B = jB * 128 + 16 * wid;

  const char* kbase = (const char*)(kbm + (size_t)b * SEQ * HDIM);
  const char* vbase = (const char*)(vt  + (size_t)b * SEQ * HDIM);

  const unsigned short* qrowA = qb + ((size_t)b * SEQ + tq0A + p) * HDIM;
  const bf16x8 qfA0 = *(const bf16x8*)(qrowA + 8 * g);
  const bf16x8 qfA1 = *(const bf16x8*)(qrowA + 32 + 8 * g);
  const unsigned short* qrowB = qb + ((size_t)b * SEQ + tq0B + p) * HDIM;
  const bf16x8 qfB0 = *(const bf16x8*)(qrowB + 8 * g);
  const bf16x8 qfB1 = *(const bf16x8*)(qrowB + 32 + 8 * g);

  const int slot = tid * 16;
  const int r0 = slot >> 7, koff = r0 * 128 + ((slot & 127) ^ ((r0 & 7) << 4));

  const int swz = (p & 7) << 4;
  const int cA0 = (16 * g) ^ swz, cA1 = (64 + 16 * g) ^ swz;

  const int srcA = (g & 1) * 32 + p;
  const int srcB = srcA + 16;
  const bool hi = (g >> 1) != 0;

  float mA = -1e30f, lA = 0.f, mB = -1e30f, lB = 0.f;
  f32x4 oA[4], oB[4];
#pragma unroll
  for (int mi = 0; mi < 4; ++mi) {
    oA[mi] = (f32x4){0.f, 0.f, 0.f, 0.f};
    oB[mi] = (f32x4){0.f, 0.f, 0.f, 0.f};
  }

  const int cnt = (66 - sp + NSPLIT - 1) / NSPLIT;   // 8 or 9

  bf16x8 rk0, rv0;
  {
    int kt; bool isA, diag;
    item_map128(sp, nA, nB, kt, isA, diag);
    rk0 = *(const bf16x8*)(kbase + (size_t)kt * 8192 + koff);
    rv0 = *(const bf16x8*)(vbase + (size_t)kt * 8192 + koff);
  }
  *(bf16x8*)((char*)sK[0] + slot) = rk0;
  *(bf16x8*)((char*)sV[0] + slot) = rv0;
  if (cnt > 1) {
    int kt; bool isA, diag;
    item_map128(sp + NSPLIT, nA, nB, kt, isA, diag);
    rk0 = *(const bf16x8*)(kbase + (size_t)kt * 8192 + koff);
    rv0 = *(const bf16x8*)(vbase + (size_t)kt * 8192 + koff);
  }
  __syncthreads();

  for (int ii = 0; ii < cnt; ++ii) {
    const int buf = ii & 1;
    if (ii + 1 < cnt) {
      const int nb = buf ^ 1;
      *(bf16x8*)((char*)sK[nb] + slot) = rk0;
      *(bf16x8*)((char*)sV[nb] + slot) = rv0;
    }
    if (ii + 2 < cnt) {                   // T14 issue-early
      int kt; bool isA, diag;
      item_map128(sp + (ii + 2) * NSPLIT, nA, nB, kt, isA, diag);
      rk0 = *(const bf16x8*)(kbase + (size_t)kt * 8192 + koff);
      rv0 = *(const bf16x8*)(vbase + (size_t)kt * 8192 + koff);
    }
    int kt; bool isA, diag;
    item_map128(sp + ii * NSPLIT, nA, nB, kt, isA, diag);
    if (isA) {
      tile_body_lds(sK[buf], sV[buf], tq0A + p - kt * 64, diag, qfA0, qfA1,
                    p, g, cA0, cA1, srcA, srcB, hi, mA, lA, oA);
    } else {
      tile_body_lds(sK[buf], sV[buf], tq0B + p - kt * 64, diag, qfB0, qfB1,
                    p, g, cA0, cA1, srcA, srcB, hi, mB, lB, oB);
    }
    __syncthreads();                      // single barrier per item
  }

  lA += __shfl_xor(lA, 16); lA += __shfl_xor(lA, 32);
  lB += __shfl_xor(lB, 16); lB += __shfl_xor(lB, 32);

  {
    const int grpA = j * 8 + wid;                    // 0..127
    float* pp = pw + ((size_t)(b * 256 + grpA) * NSPLIT + sp) * 1056;
#pragma unroll
    for (int mi = 0; mi < 4; ++mi)
      *(f32x4*)(pp + p * 64 + 16 * mi + 4 * g) = oA[mi];
    if (g == 0) { pp[1024 + p] = mA; pp[1040 + p] = lA; }
  }
  {
    const int grpB = jB * 8 + wid;                   // 128..255
    float* pp = pw + ((size_t)(b * 256 + grpB) * NSPLIT + sp) * 1056;
#pragma unroll
    for (int mi = 0; mi < 4; ++mi)
      *(f32x4*)(pp + p * 64 + 16 * mi + 4 * g) = oB[mi];
    if (g == 0) { pp[1024 + p] = mB; pp[1040 + p] = lB; }
  }
}

// ---- stage 2: merge NSPLIT partials per (batch, 16-query group), normalize -
__global__ __launch_bounds__(256) void attn_merge_kernel(
    const float* __restrict__ pw, float* __restrict__ out) {
  const int bid = blockIdx.x;                   // b*256 + grp
  const int b = bid >> 8, grp = bid & 255;
  const int q = threadIdx.x & 15, db = threadIdx.x >> 4;
  const float* pp = pw + (size_t)bid * NSPLIT * 1056;
  float ms[NSPLIT], ls[NSPLIT];
  float mm = -3e38f;
#pragma unroll
  for (int s = 0; s < NSPLIT; ++s) {
    ms[s] = pp[s * 1056 + 1024 + q];
    ls[s] = pp[s * 1056 + 1040 + q];
    mm = fmaxf(mm, ms[s]);
  }
  float L = 0.f, a0 = 0.f, a1 = 0.f, a2 = 0.f, a3 = 0.f;
#pragma unroll
  for (int s = 0; s < NSPLIT; ++s) {
    float sc = fexp2(ms[s] - mm);
    L += ls[s] * sc;
    float4 v = *(const float4*)(pp + s * 1056 + q * 64 + 4 * db);
    a0 += v.x * sc; a1 += v.y * sc; a2 += v.z * sc; a3 += v.w * sc;
  }
  const float inv = 1.f / L;
  float* op = out + ((size_t)b * SEQ + grp * 16 + q) * HDIM + 4 * db;
  op[0] = a0 * inv; op[1] = a1 * inv; op[2] = a2 * inv; op[3] = a3 * inv;
}

extern "C" void kernel_launch(void* const* d_in, const int* in_sizes, int n_in,
                              void* d_out, int out_size, void* d_ws, size_t ws_size,
                              hipStream_t stream) {
  const float* x  = (const float*)d_in[0];
  const float* Wq = (const float*)d_in[1];
  const float* Wk = (const float*)d_in[2];
  const float* Wv = (const float*)d_in[3];
  float* outp = (float*)d_out;

  const size_t rows = (size_t)BATCH * SEQ;        // 16384
  unsigned short* qbf = (unsigned short*)d_ws;
  unsigned short* kbf = qbf + rows * HDIM;
  unsigned short* vtb = kbf + rows * HDIM;
  unsigned short* wt  = vtb + rows * HDIM;        // 192*1024 bf16
  float* pw = (float*)(wt + 192 * 1024);          // 8192 partials x 1056 f32

  wt_kernel<<<dim3(48), dim3(256), 0, stream>>>(Wq, Wk, Wv, wt);
  qkv_mfma_kernel<<<dim3((unsigned)(rows / 64)), dim3(512), 0, stream>>>(x, wt, qbf, kbf, vtb);
  attn_partial_kernel<<<dim3(512), dim3(512), 0, stream>>>(qbf, kbf, vtb, pw);
  attn_merge_kernel<<<dim3(1024), dim3(256), 0, stream>>>(pw, outp);
}

// Round 21
// 58.266 us; speedup vs baseline: 1.1301x; 1.1301x over previous
//
#include <hip/hip_runtime.h>
#include <math.h>

#define BATCH 4
#define SEQ   4096
#define EMB   1024
#define HDIM  64
#define NSPLIT 4

typedef __attribute__((ext_vector_type(8))) short bf16x8;
typedef __attribute__((ext_vector_type(4))) float f32x4;
typedef __attribute__((ext_vector_type(4))) unsigned int u32x4;

#define MFMA16(a, b, c) __builtin_amdgcn_mfma_f32_16x16x32_bf16(a, b, c, 0, 0, 0)

__device__ __forceinline__ unsigned short f2bf(float f) {
  unsigned int u = __float_as_uint(f);
  u = (u + 0x7FFFu + ((u >> 16) & 1u)) >> 16;   // RNE
  return (unsigned short)u;
}

__device__ __forceinline__ float fexp2(float x) {  // 2^x, hw v_exp_f32
  float r;
  asm("v_exp_f32 %0, %1" : "=v"(r) : "v"(x));
  return r;
}

// ---- W pre-transpose: W[1024][64] f32 x3 -> Wt[192][1024] bf16 --------------
__global__ __launch_bounds__(256) void wt_kernel(
    const float* __restrict__ Wq, const float* __restrict__ Wk,
    const float* __restrict__ Wv, unsigned short* __restrict__ wt) {
  __shared__ float tile[64][65];
  const int bid = blockIdx.x;           // 48 = 3 matrices x 16 k-tiles
  const int m = bid >> 4, kt = bid & 15;
  const float* W = (m == 0) ? Wq : (m == 1) ? Wk : Wv;
  const int tid = threadIdx.x;
  {
    const int r = tid >> 2, c4 = tid & 3;
    const float* src = W + (size_t)(kt * 64 + r) * 64 + c4 * 16;
#pragma unroll
    for (int j = 0; j < 4; ++j) {
      float4 a = *(const float4*)(src + j * 4);
      tile[r][c4 * 16 + j * 4 + 0] = a.x;
      tile[r][c4 * 16 + j * 4 + 1] = a.y;
      tile[r][c4 * 16 + j * 4 + 2] = a.z;
      tile[r][c4 * 16 + j * 4 + 3] = a.w;
    }
  }
  __syncthreads();
  {
    const int col = tid >> 2, kq = tid & 3;
    unsigned short o[16];
#pragma unroll
    for (int j = 0; j < 16; ++j) o[j] = f2bf(tile[kq * 16 + j][col]);
    unsigned short* dst = wt + (size_t)(m * 64 + col) * 1024 + kt * 64 + kq * 16;
    *(bf16x8*)(dst)     = *(bf16x8*)&o[0];
    *(bf16x8*)(dst + 8) = *(bf16x8*)&o[8];
  }
}

// ---------------- QKV projection via MFMA: 64-row M-tile, 8 waves (r18) -----
__global__ __launch_bounds__(512) void qkv_mfma_kernel(
    const float* __restrict__ x, const unsigned short* __restrict__ wt,
    unsigned short* __restrict__ qb, unsigned short* __restrict__ kb,
    unsigned short* __restrict__ vt) {
  __shared__ __align__(16) unsigned short xs[64 * 64];
  __shared__ __align__(16) unsigned short ws[192 * 64];
  const int tid  = threadIdx.x;
  const int lane = tid & 63, wid = tid >> 6;
  const int g = lane >> 4, p = lane & 15;
  const int mt = wid >> 2, wq = wid & 3;
  const size_t row0 = (size_t)blockIdx.x * 64;

  const int sr = tid >> 3, sc = tid & 7;
  const float* xp = x + (row0 + sr) * EMB + sc * 8;

  f32x4 acc[2][3];
#pragma unroll
  for (int rt = 0; rt < 2; ++rt)
#pragma unroll
    for (int ct = 0; ct < 3; ++ct) acc[rt][ct] = (f32x4){0.f, 0.f, 0.f, 0.f};

  float4 rx[2];
  bf16x8 rw[3];
#pragma unroll
  for (int j = 0; j < 2; ++j) rx[j] = *(const float4*)(xp + j * 4);
#pragma unroll
  for (int it = 0; it < 3; ++it) {
    int i = tid + it * 512, col = i >> 3, cc = i & 7;
    rw[it] = *(const bf16x8*)(wt + (size_t)col * 1024 + cc * 8);
  }

  for (int kc = 0; kc < 16; ++kc) {
    __syncthreads();
#pragma unroll
    for (int j = 0; j < 2; ++j) {
      ushort4 h;
      h.x = f2bf(rx[j].x); h.y = f2bf(rx[j].y);
      h.z = f2bf(rx[j].z); h.w = f2bf(rx[j].w);
      *(ushort4*)((char*)xs + ((sr * 128 + sc * 16 + j * 8) ^ ((sr & 7) << 4))) = h;
    }
#pragma unroll
    for (int it = 0; it < 3; ++it) {
      int i = tid + it * 512, col = i >> 3, cc = i & 7;
      *(bf16x8*)((char*)ws + ((col * 128 + cc * 16) ^ ((col & 7) << 4))) = rw[it];
    }
    if (kc < 15) {
      const float* xpn = xp + (kc + 1) * 64;
#pragma unroll
      for (int j = 0; j < 2; ++j) rx[j] = *(const float4*)(xpn + j * 4);
#pragma unroll
      for (int it = 0; it < 3; ++it) {
        int i = tid + it * 512, col = i >> 3, cc = i & 7;
        rw[it] = *(const bf16x8*)(wt + (size_t)col * 1024 + (kc + 1) * 64 + cc * 8);
      }
    }
    __syncthreads();
#pragma unroll
    for (int ks = 0; ks < 2; ++ks) {
      bf16x8 af[2];
#pragma unroll
      for (int rt = 0; rt < 2; ++rt) {
        int row = mt * 32 + rt * 16 + p;
        af[rt] = *(const bf16x8*)((char*)xs +
                 ((row * 128 + ks * 64 + g * 16) ^ ((row & 7) << 4)));
      }
#pragma unroll
      for (int ct = 0; ct < 3; ++ct) {
        int col = wq * 48 + ct * 16 + p;
        bf16x8 bfr = *(const bf16x8*)((char*)ws +
                     ((col * 128 + ks * 64 + g * 16) ^ ((col & 7) << 4)));
#pragma unroll
        for (int rt = 0; rt < 2; ++rt)
          acc[rt][ct] = MFMA16(af[rt], bfr, acc[rt][ct]);
      }
    }
  }

  const int b     = (int)(row0 >> 12);
  const int tbase = (int)(row0 & 4095);
  unsigned short* vtb = vt + (((size_t)b * 64 + (tbase >> 6)) * 64) * 64;
#pragma unroll
  for (int rt = 0; rt < 2; ++rt)
#pragma unroll
    for (int ct = 0; ct < 3; ++ct) {
      const int c0  = wq * 48 + ct * 16;
      const int mtx = c0 >> 6;
      const int col = (c0 & 63) + p;
#pragma unroll
      for (int r = 0; r < 4; ++r) {
        const int row = mt * 32 + rt * 16 + 4 * g + r;
        const float vf = acc[rt][ct][r];
        if (mtx == 0)      qb[(row0 + row) * HDIM + col] = f2bf(vf * 0.0450843714f);
        else if (mtx == 1) kb[(row0 + row) * HDIM + col] = f2bf(vf);
        else               vtb[(size_t)col * 64 + row]   = f2bf(vf);
      }
    }
}

// ---- one 64-key tile from swizzled LDS; cvt_pk + word-shuffle transpose ----
__device__ __forceinline__ void tile_body_lds(
    const unsigned short* __restrict__ sKb, const unsigned short* __restrict__ sVb,
    int qrel, bool diag,
    const bf16x8& qf0, const bf16x8& qf1,
    int p, int g, int cA0, int cA1, int srcA, int srcB, bool hi,
    float& m, float& l, f32x4 (&o)[4]) {
  f32x4 sc4[4];
#pragma unroll
  for (int t = 0; t < 4; ++t) {
    const int row = 16 * t + p;
    bf16x8 a0 = *(const bf16x8*)((const char*)sKb + row * 128 + cA0);
    bf16x8 a1 = *(const bf16x8*)((const char*)sKb + row * 128 + cA1);
    f32x4 a = (f32x4){0.f, 0.f, 0.f, 0.f};
    a = MFMA16(a0, qf0, a);
    a = MFMA16(a1, qf1, a);
    sc4[t] = a;
  }
  if (diag) {
#pragma unroll
    for (int t = 0; t < 4; ++t)
#pragma unroll
      for (int r = 0; r < 4; ++r)
        if (16 * t + 4 * g + r > qrel) sc4[t][r] = -1e30f;
  }
  float tm = -3e38f;
#pragma unroll
  for (int t = 0; t < 4; ++t)
#pragma unroll
    for (int r = 0; r < 4; ++r) tm = fmaxf(tm, sc4[t][r]);
  tm = fmaxf(tm, __shfl_xor(tm, 16));
  tm = fmaxf(tm, __shfl_xor(tm, 32));
  if (__any(tm > m + 11.5f)) {               // defer-max (T13)
    float mn = fmaxf(m, tm);
    float c = fexp2(m - mn);
    l *= c;
#pragma unroll
    for (int mi = 0; mi < 4; ++mi) o[mi] *= c;
    m = mn;
  }
  float psum = 0.f;
#pragma unroll
  for (int t = 0; t < 4; ++t)
#pragma unroll
    for (int r = 0; r < 4; ++r) {
      float pv = fexp2(sc4[t][r] - m);
      sc4[t][r] = pv;
      psum += pv;
    }
  l += psum;
  unsigned int pk[4][2];
#pragma unroll
  for (int t = 0; t < 4; ++t) {
    asm("v_cvt_pk_bf16_f32 %0, %1, %2"
        : "=v"(pk[t][0]) : "v"(sc4[t][0]), "v"(sc4[t][1]));
    asm("v_cvt_pk_bf16_f32 %0, %1, %2"
        : "=v"(pk[t][1]) : "v"(sc4[t][2]), "v"(sc4[t][3]));
  }
  u32x4 wb0, wb1;
#pragma unroll
  for (int h2 = 0; h2 < 2; ++h2) {
    const int src = h2 ? srcB : srcA;
    unsigned c0 = (unsigned)__shfl((int)pk[0][0], src);
    unsigned c1 = (unsigned)__shfl((int)pk[1][0], src);
    wb0[2 * h2 + 0] = hi ? c1 : c0;
    unsigned d0 = (unsigned)__shfl((int)pk[0][1], src);
    unsigned d1 = (unsigned)__shfl((int)pk[1][1], src);
    wb0[2 * h2 + 1] = hi ? d1 : d0;
    unsigned e0 = (unsigned)__shfl((int)pk[2][0], src);
    unsigned e1 = (unsigned)__shfl((int)pk[3][0], src);
    wb1[2 * h2 + 0] = hi ? e1 : e0;
    unsigned f0 = (unsigned)__shfl((int)pk[2][1], src);
    unsigned f1 = (unsigned)__shfl((int)pk[3][1], src);
    wb1[2 * h2 + 1] = hi ? f1 : f0;
  }
  bf16x8 b0 = __builtin_bit_cast(bf16x8, wb0);
  bf16x8 b1 = __builtin_bit_cast(bf16x8, wb1);
#pragma unroll
  for (int mi = 0; mi < 4; ++mi) {
    const int rowv = 16 * mi + p;
    bf16x8 va0 = *(const bf16x8*)((const char*)sVb + rowv * 128 + cA0);
    bf16x8 va1 = *(const bf16x8*)((const char*)sVb + rowv * 128 + cA1);
    o[mi] = MFMA16(va0, b0, o[mi]);
    o[mi] = MFMA16(va1, b1, o[mi]);
  }
}

// pair (j, 31-j) of 128-row q-blocks; nA=2j+2, nB=64-2j, 66 items total.
__device__ __forceinline__ void item_map128(int g_it, int nA, int nB,
                                            int& kt, bool& isA, bool& diag) {
  if (g_it < nA) { isA = true;  kt = g_it;      diag = (kt >= nA - 2); }
  else           { isA = false; kt = g_it - nA; diag = (kt >= nB - 2); }
}

// ---- flash attention stage 1: 128-row Q pairs, TWO items per barrier -------
// 4 LDS buffers (64KB). Each barrier period: write pair k+1 from regs, issue
// loads for pair k+2, then run BOTH tile bodies back-to-back (no barrier
// between) -> compiler overlaps item i1's ds_read/QK^T with i0's softmax/PV.
// Barriers per block halved (17 -> 9). Grid 256 x 512thr, NSPLIT=4.
__global__ __launch_bounds__(512) void attn_partial_kernel(
    const unsigned short* __restrict__ qb, const unsigned short* __restrict__ kbm,
    const unsigned short* __restrict__ vt, float* __restrict__ pw) {
  __shared__ __align__(16) unsigned short sK[4][4096];
  __shared__ __align__(16) unsigned short sV[4][4096];
  const int tid = threadIdx.x;
  const int wid = tid >> 6, lane = tid & 63;     // wid 0..7
  const int g = lane >> 4, p = lane & 15;
  const int bid = blockIdx.x;
  const int sp = bid & 3, j = (bid >> 2) & 15, b = bid >> 6;
  const int jB = 31 - j;
  const int nA = 2 * j + 2, nB = 64 - 2 * j;     // nA+nB == 66
  const int tq0A = j * 128 + 16 * wid;
  const int tq0B = jB * 128 + 16 * wid;

  const char* kbase = (const char*)(kbm + (size_t)b * SEQ * HDIM);
  const char* vbase = (const char*)(vt  + (size_t)b * SEQ * HDIM);

  const unsigned short* qrowA = qb + ((size_t)b * SEQ + tq0A + p) * HDIM;
  const bf16x8 qfA0 = *(const bf16x8*)(qrowA + 8 * g);
  const bf16x8 qfA1 = *(const bf16x8*)(qrowA + 32 + 8 * g);
  const unsigned short* qrowB = qb + ((size_t)b * SEQ + tq0B + p) * HDIM;
  const bf16x8 qfB0 = *(const bf16x8*)(qrowB + 8 * g);
  const bf16x8 qfB1 = *(const bf16x8*)(qrowB + 32 + 8 * g);

  const int slot = tid * 16;
  const int r0 = slot >> 7, koff = r0 * 128 + ((slot & 127) ^ ((r0 & 7) << 4));

  const int swz = (p & 7) << 4;
  const int cA0 = (16 * g) ^ swz, cA1 = (64 + 16 * g) ^ swz;

  const int srcA = (g & 1) * 32 + p;
  const int srcB = srcA + 16;
  const bool hi = (g >> 1) != 0;

  float mA = -1e30f, lA = 0.f, mB = -1e30f, lB = 0.f;
  f32x4 oA[4], oB[4];
#pragma unroll
  for (int mi = 0; mi < 4; ++mi) {
    oA[mi] = (f32x4){0.f, 0.f, 0.f, 0.f};
    oB[mi] = (f32x4){0.f, 0.f, 0.f, 0.f};
  }

  const int cnt = (66 - sp + NSPLIT - 1) / NSPLIT;   // 16 or 17

#define LOAD_ITEM(i, rk, rv) do {                                        \
    int kt_; bool isA_, diag_;                                           \
    item_map128(sp + (i) * NSPLIT, nA, nB, kt_, isA_, diag_);            \
    rk = *(const bf16x8*)(kbase + (size_t)kt_ * 8192 + koff);            \
    rv = *(const bf16x8*)(vbase + (size_t)kt_ * 8192 + koff);            \
  } while (0)

#define WRITE_BUF(bi, rk, rv) do {                                       \
    *(bf16x8*)((char*)sK[bi] + slot) = rk;                               \
    *(bf16x8*)((char*)sV[bi] + slot) = rv;                               \
  } while (0)

#define PROC_ITEM(i, bi) do {                                            \
    int kt_; bool isA_, diag_;                                           \
    item_map128(sp + (i) * NSPLIT, nA, nB, kt_, isA_, diag_);            \
    if (isA_) tile_body_lds(sK[bi], sV[bi], tq0A + p - kt_ * 64, diag_,  \
                            qfA0, qfA1, p, g, cA0, cA1, srcA, srcB, hi,  \
                            mA, lA, oA);                                 \
    else      tile_body_lds(sK[bi], sV[bi], tq0B + p - kt_ * 64, diag_,  \
                            qfB0, qfB1, p, g, cA0, cA1, srcA, srcB, hi,  \
                            mB, lB, oB);                                 \
  } while (0)

  bf16x8 rka, rva, rkb, rvb;
  // prologue: stage items 0,1 into bufs 0,1; preload items 2,3 into regs
  LOAD_ITEM(0, rka, rva);
  WRITE_BUF(0, rka, rva);
  if (cnt > 1) { LOAD_ITEM(1, rkb, rvb); WRITE_BUF(1, rkb, rvb); }
  if (cnt > 2) LOAD_ITEM(2, rka, rva);
  if (cnt > 3) LOAD_ITEM(3, rkb, rvb);
  __syncthreads();

  const int npairs = (cnt + 1) >> 1;
  for (int pr = 0; pr < npairs; ++pr) {
    const int base = (pr & 1) * 2, nxt = base ^ 2;
    const int i0 = 2 * pr, i1 = 2 * pr + 1;
    if (i0 + 2 < cnt) WRITE_BUF(nxt + 0, rka, rva);
    if (i1 + 2 < cnt) WRITE_BUF(nxt + 1, rkb, rvb);
    if (i0 + 4 < cnt) LOAD_ITEM(i0 + 4, rka, rva);   // T14 issue-early
    if (i1 + 4 < cnt) LOAD_ITEM(i1 + 4, rkb, rvb);
    PROC_ITEM(i0, base + 0);
    if (i1 < cnt) PROC_ITEM(i1, base + 1);
    __syncthreads();                    // one barrier per PAIR of items
  }

#undef LOAD_ITEM
#undef WRITE_BUF
#undef PROC_ITEM

  lA += __shfl_xor(lA, 16); lA += __shfl_xor(lA, 32);
  lB += __shfl_xor(lB, 16); lB += __shfl_xor(lB, 32);

  {
    const int grpA = j * 8 + wid;                    // 0..127
    float* pp = pw + ((size_t)(b * 256 + grpA) * NSPLIT + sp) * 1056;
#pragma unroll
    for (int mi = 0; mi < 4; ++mi)
      *(f32x4*)(pp + p * 64 + 16 * mi + 4 * g) = oA[mi];
    if (g == 0) { pp[1024 + p] = mA; pp[1040 + p] = lA; }
  }
  {
    const int grpB = jB * 8 + wid;                   // 128..255
    float* pp = pw + ((size_t)(b * 256 + grpB) * NSPLIT + sp) * 1056;
#pragma unroll
    for (int mi = 0; mi < 4; ++mi)
      *(f32x4*)(pp + p * 64 + 16 * mi + 4 * g) = oB[mi];
    if (g == 0) { pp[1024 + p] = mB; pp[1040 + p] = lB; }
  }
}

// ---- stage 2: merge NSPLIT partials per (batch, 16-query group), normalize -
__global__ __launch_bounds__(256) void attn_merge_kernel(
    const float* __restrict__ pw, float* __restrict__ out) {
  const int bid = blockIdx.x;                   // b*256 + grp
  const int b = bid >> 8, grp = bid & 255;
  const int q = threadIdx.x & 15, db = threadIdx.x >> 4;
  const float* pp = pw + (size_t)bid * NSPLIT * 1056;
  float ms[NSPLIT], ls[NSPLIT];
  float mm = -3e38f;
#pragma unroll
  for (int s = 0; s < NSPLIT; ++s) {
    ms[s] = pp[s * 1056 + 1024 + q];
    ls[s] = pp[s * 1056 + 1040 + q];
    mm = fmaxf(mm, ms[s]);
  }
  float L = 0.f, a0 = 0.f, a1 = 0.f, a2 = 0.f, a3 = 0.f;
#pragma unroll
  for (int s = 0; s < NSPLIT; ++s) {
    float sc = fexp2(ms[s] - mm);
    L += ls[s] * sc;
    float4 v = *(const float4*)(pp + s * 1056 + q * 64 + 4 * db);
    a0 += v.x * sc; a1 += v.y * sc; a2 += v.z * sc; a3 += v.w * sc;
  }
  const float inv = 1.f / L;
  float* op = out + ((size_t)b * SEQ + grp * 16 + q) * HDIM + 4 * db;
  op[0] = a0 * inv; op[1] = a1 * inv; op[2] = a2 * inv; op[3] = a3 * inv;
}

extern "C" void kernel_launch(void* const* d_in, const int* in_sizes, int n_in,
                              void* d_out, int out_size, void* d_ws, size_t ws_size,
                              hipStream_t stream) {
  const float* x  = (const float*)d_in[0];
  const float* Wq = (const float*)d_in[1];
  const float* Wk = (const float*)d_in[2];
  const float* Wv = (const float*)d_in[3];
  float* outp = (float*)d_out;

  const size_t rows = (size_t)BATCH * SEQ;        // 16384
  unsigned short* qbf = (unsigned short*)d_ws;
  unsigned short* kbf = qbf + rows * HDIM;
  unsigned short* vtb = kbf + rows * HDIM;
  unsigned short* wt  = vtb + rows * HDIM;        // 192*1024 bf16
  float* pw = (float*)(wt + 192 * 1024);          // 4096 partials x 1056 f32

  wt_kernel<<<dim3(48), dim3(256), 0, stream>>>(Wq, Wk, Wv, wt);
  qkv_mfma_kernel<<<dim3((unsigned)(rows / 64)), dim3(512), 0, stream>>>(x, wt, qbf, kbf, vtb);
  attn_partial_kernel<<<dim3(256), dim3(512), 0, stream>>>(qbf, kbf, vtb, pw);
  attn_merge_kernel<<<dim3(1024), dim3(256), 0, stream>>>(pw, outp);
}

// Round 22
// 56.608 us; speedup vs baseline: 1.1632x; 1.0293x over previous
//
#include <hip/hip_runtime.h>
#include <math.h>

#define BATCH 4
#define SEQ   4096
#define EMB   1024
#define HDIM  64
#define NSPLIT 4

typedef __attribute__((ext_vector_type(8))) short bf16x8;
typedef __attribute__((ext_vector_type(4))) float f32x4;
typedef __attribute__((ext_vector_type(16))) float f32x16;
typedef __attribute__((ext_vector_type(4))) unsigned int u32x4;

#define MFMA16(a, b, c) __builtin_amdgcn_mfma_f32_16x16x32_bf16(a, b, c, 0, 0, 0)
#define MFMA32(a, b, c) __builtin_amdgcn_mfma_f32_32x32x16_bf16(a, b, c, 0, 0, 0)
#define ZERO16 (f32x16){0.f,0.f,0.f,0.f,0.f,0.f,0.f,0.f,0.f,0.f,0.f,0.f,0.f,0.f,0.f,0.f}

__device__ __forceinline__ unsigned short f2bf(float f) {
  unsigned int u = __float_as_uint(f);
  u = (u + 0x7FFFu + ((u >> 16) & 1u)) >> 16;   // RNE
  return (unsigned short)u;
}

__device__ __forceinline__ float fexp2(float x) {  // 2^x, hw v_exp_f32
  float r;
  asm("v_exp_f32 %0, %1" : "=v"(r) : "v"(x));
  return r;
}

// ---- W pre-transpose: W[1024][64] f32 x3 -> Wt[192][1024] bf16 --------------
__global__ __launch_bounds__(256) void wt_kernel(
    const float* __restrict__ Wq, const float* __restrict__ Wk,
    const float* __restrict__ Wv, unsigned short* __restrict__ wt) {
  __shared__ float tile[64][65];
  const int bid = blockIdx.x;           // 48 = 3 matrices x 16 k-tiles
  const int m = bid >> 4, kt = bid & 15;
  const float* W = (m == 0) ? Wq : (m == 1) ? Wk : Wv;
  const int tid = threadIdx.x;
  {
    const int r = tid >> 2, c4 = tid & 3;
    const float* src = W + (size_t)(kt * 64 + r) * 64 + c4 * 16;
#pragma unroll
    for (int j = 0; j < 4; ++j) {
      float4 a = *(const float4*)(src + j * 4);
      tile[r][c4 * 16 + j * 4 + 0] = a.x;
      tile[r][c4 * 16 + j * 4 + 1] = a.y;
      tile[r][c4 * 16 + j * 4 + 2] = a.z;
      tile[r][c4 * 16 + j * 4 + 3] = a.w;
    }
  }
  __syncthreads();
  {
    const int col = tid >> 2, kq = tid & 3;
    unsigned short o[16];
#pragma unroll
    for (int j = 0; j < 16; ++j) o[j] = f2bf(tile[kq * 16 + j][col]);
    unsigned short* dst = wt + (size_t)(m * 64 + col) * 1024 + kt * 64 + kq * 16;
    *(bf16x8*)(dst)     = *(bf16x8*)&o[0];
    *(bf16x8*)(dst + 8) = *(bf16x8*)&o[8];
  }
}

// ---------------- QKV projection via MFMA: 64-row M-tile, 8 waves (r18) -----
__global__ __launch_bounds__(512) void qkv_mfma_kernel(
    const float* __restrict__ x, const unsigned short* __restrict__ wt,
    unsigned short* __restrict__ qb, unsigned short* __restrict__ kb,
    unsigned short* __restrict__ vt) {
  __shared__ __align__(16) unsigned short xs[64 * 64];
  __shared__ __align__(16) unsigned short ws[192 * 64];
  const int tid  = threadIdx.x;
  const int lane = tid & 63, wid = tid >> 6;
  const int g = lane >> 4, p = lane & 15;
  const int mt = wid >> 2, wq = wid & 3;
  const size_t row0 = (size_t)blockIdx.x * 64;

  const int sr = tid >> 3, sc = tid & 7;
  const float* xp = x + (row0 + sr) * EMB + sc * 8;

  f32x4 acc[2][3];
#pragma unroll
  for (int rt = 0; rt < 2; ++rt)
#pragma unroll
    for (int ct = 0; ct < 3; ++ct) acc[rt][ct] = (f32x4){0.f, 0.f, 0.f, 0.f};

  float4 rx[2];
  bf16x8 rw[3];
#pragma unroll
  for (int j = 0; j < 2; ++j) rx[j] = *(const float4*)(xp + j * 4);
#pragma unroll
  for (int it = 0; it < 3; ++it) {
    int i = tid + it * 512, col = i >> 3, cc = i & 7;
    rw[it] = *(const bf16x8*)(wt + (size_t)col * 1024 + cc * 8);
  }

  for (int kc = 0; kc < 16; ++kc) {
    __syncthreads();
#pragma unroll
    for (int j = 0; j < 2; ++j) {
      ushort4 h;
      h.x = f2bf(rx[j].x); h.y = f2bf(rx[j].y);
      h.z = f2bf(rx[j].z); h.w = f2bf(rx[j].w);
      *(ushort4*)((char*)xs + ((sr * 128 + sc * 16 + j * 8) ^ ((sr & 7) << 4))) = h;
    }
#pragma unroll
    for (int it = 0; it < 3; ++it) {
      int i = tid + it * 512, col = i >> 3, cc = i & 7;
      *(bf16x8*)((char*)ws + ((col * 128 + cc * 16) ^ ((col & 7) << 4))) = rw[it];
    }
    if (kc < 15) {
      const float* xpn = xp + (kc + 1) * 64;
#pragma unroll
      for (int j = 0; j < 2; ++j) rx[j] = *(const float4*)(xpn + j * 4);
#pragma unroll
      for (int it = 0; it < 3; ++it) {
        int i = tid + it * 512, col = i >> 3, cc = i & 7;
        rw[it] = *(const bf16x8*)(wt + (size_t)col * 1024 + (kc + 1) * 64 + cc * 8);
      }
    }
    __syncthreads();
#pragma unroll
    for (int ks = 0; ks < 2; ++ks) {
      bf16x8 af[2];
#pragma unroll
      for (int rt = 0; rt < 2; ++rt) {
        int row = mt * 32 + rt * 16 + p;
        af[rt] = *(const bf16x8*)((char*)xs +
                 ((row * 128 + ks * 64 + g * 16) ^ ((row & 7) << 4)));
      }
#pragma unroll
      for (int ct = 0; ct < 3; ++ct) {
        int col = wq * 48 + ct * 16 + p;
        bf16x8 bfr = *(const bf16x8*)((char*)ws +
                     ((col * 128 + ks * 64 + g * 16) ^ ((col & 7) << 4)));
#pragma unroll
        for (int rt = 0; rt < 2; ++rt)
          acc[rt][ct] = MFMA16(af[rt], bfr, acc[rt][ct]);
      }
    }
  }

  const int b     = (int)(row0 >> 12);
  const int tbase = (int)(row0 & 4095);
  unsigned short* vtb = vt + (((size_t)b * 64 + (tbase >> 6)) * 64) * 64;
#pragma unroll
  for (int rt = 0; rt < 2; ++rt)
#pragma unroll
    for (int ct = 0; ct < 3; ++ct) {
      const int c0  = wq * 48 + ct * 16;
      const int mtx = c0 >> 6;
      const int col = (c0 & 63) + p;
#pragma unroll
      for (int r = 0; r < 4; ++r) {
        const int row = mt * 32 + rt * 16 + 4 * g + r;
        const float vf = acc[rt][ct][r];
        if (mtx == 0)      qb[(row0 + row) * HDIM + col] = f2bf(vf * 0.0450843714f);
        else if (mtx == 1) kb[(row0 + row) * HDIM + col] = f2bf(vf);
        else               vtb[(size_t)col * 64 + row]   = f2bf(vf);
      }
    }
}

// ---- one 64-key tile, 32x32 MFMA: 32 queries/wave, in-lane softmax ---------
// C/D map (verified): col=lane&31 (query for S^T / dim-free), row=(reg&3)+
// 8*(reg>>2)+4*(lane>>5). A/B k-slot map assumed k=8*(lane>>5)+e for BOTH
// operands of each MFMA (cancels through shared slots). Each query's 64-key
// row lives in lane & lane+32 -> 1 shfl_xor(32) reduce; P^T B-frags built with
// 16 cvt_pk + 16 word shfl_xor(32) + selects (no generic transpose).
__device__ __forceinline__ void tile_body32(
    const unsigned short* __restrict__ sKb, const unsigned short* __restrict__ sVb,
    int qrel, bool diag, const bf16x8 (&qf)[4], int h, int q5,
    float& m, float& l, f32x16& o0, f32x16& o1) {
  const int sw = (q5 & 7) << 4;             // (32+q5)&7 == q5&7
  f32x16 s0 = ZERO16, s1 = ZERO16;
#pragma unroll
  for (int st = 0; st < 4; ++st) {
    bf16x8 k0 = *(const bf16x8*)((const char*)sKb + q5 * 128 +
                                 ((32 * st + 16 * h) ^ sw));
    bf16x8 k1 = *(const bf16x8*)((const char*)sKb + (32 + q5) * 128 +
                                 ((32 * st + 16 * h) ^ sw));
    s0 = MFMA32(k0, qf[st], s0);
    s1 = MFMA32(k1, qf[st], s1);
  }
  if (diag) {
#pragma unroll
    for (int r = 0; r < 16; ++r) {
      const int kk = (r & 3) + 8 * (r >> 2) + 4 * h;
      if (kk      > qrel) s0[r] = -1e30f;
      if (kk + 32 > qrel) s1[r] = -1e30f;
    }
  }
  float tm = -3e38f;
#pragma unroll
  for (int r = 0; r < 16; ++r) { tm = fmaxf(tm, s0[r]); tm = fmaxf(tm, s1[r]); }
  tm = fmaxf(tm, __shfl_xor(tm, 32));
  if (__any(tm > m + 11.5f)) {              // defer-max (T13)
    float mn = fmaxf(m, tm);
    float c = fexp2(m - mn);
    l *= c; o0 *= c; o1 *= c;
    m = mn;
  }
  float ps = 0.f;
#pragma unroll
  for (int r = 0; r < 16; ++r) {
    float a = fexp2(s0[r] - m); s0[r] = a; ps += a;
    float c2 = fexp2(s1[r] - m); s1[r] = c2; ps += c2;
  }
  ps += __shfl_xor(ps, 32);
  l += ps;
  // ---- pack P to bf16 words; W[i] = keys (4h+2i, 4h+2i+1) pattern per blk --
  unsigned W[16];
#pragma unroll
  for (int i = 0; i < 8; ++i) {
    asm("v_cvt_pk_bf16_f32 %0, %1, %2" : "=v"(W[i])     : "v"(s0[2*i]), "v"(s0[2*i+1]));
    asm("v_cvt_pk_bf16_f32 %0, %1, %2" : "=v"(W[8 + i]) : "v"(s1[2*i]), "v"(s1[2*i+1]));
  }
  bf16x8 pf[4];
#pragma unroll
  for (int sG = 0; sG < 4; ++sG) {
    const int ba = 4 * sG;
    unsigned x0 = (unsigned)__shfl_xor((int)W[ba + 0], 32);
    unsigned x1 = (unsigned)__shfl_xor((int)W[ba + 1], 32);
    unsigned x2 = (unsigned)__shfl_xor((int)W[ba + 2], 32);
    unsigned x3 = (unsigned)__shfl_xor((int)W[ba + 3], 32);
    u32x4 fw;
    fw[0] = h ? x2 : W[ba + 0];
    fw[1] = h ? x3 : W[ba + 1];
    fw[2] = h ? W[ba + 2] : x0;
    fw[3] = h ? W[ba + 3] : x1;
    pf[sG] = __builtin_bit_cast(bf16x8, fw);
  }
  // ---- O^T += V^T . P^T (V stored [dim][key] in LDS) ----
#pragma unroll
  for (int sG = 0; sG < 4; ++sG) {
    bf16x8 v0 = *(const bf16x8*)((const char*)sVb + q5 * 128 +
                                 ((32 * sG + 16 * h) ^ sw));
    o0 = MFMA32(v0, pf[sG], o0);
    bf16x8 v1 = *(const bf16x8*)((const char*)sVb + (32 + q5) * 128 +
                                 ((32 * sG + 16 * h) ^ sw));
    o1 = MFMA32(v1, pf[sG], o1);
  }
}

// pair (j, 31-j) of 128-row q-blocks; nA=2j+2, nB=64-2j, 66 items total.
__device__ __forceinline__ void item_map128(int g_it, int nA, int nB,
                                            int& kt, bool& isA, bool& diag) {
  if (g_it < nA) { isA = true;  kt = g_it;      diag = (kt >= nA - 2); }
  else           { isA = false; kt = g_it - nA; diag = (kt >= nB - 2); }
}

// ---- flash attention stage 1: 128-row pairs, 32x32 MFMA, side-split waves --
// Waves 0-3 own side A (32 queries each), 4-7 side B. Per item only the
// owning side's 4 waves run the body -> LDS fragment reads per item HALVED
// (the DS pipe was the measured bottleneck). Grid 256 x 512thr, NSPLIT=4.
__global__ __launch_bounds__(512) void attn_partial_kernel(
    const unsigned short* __restrict__ qb, const unsigned short* __restrict__ kbm,
    const unsigned short* __restrict__ vt, float* __restrict__ pw) {
  __shared__ __align__(16) unsigned short sK[2][4096];
  __shared__ __align__(16) unsigned short sV[2][4096];
  const int tid = threadIdx.x;
  const int wid = tid >> 6, lane = tid & 63;     // wid 0..7
  const int q5 = lane & 31, h = lane >> 5;
  const int bid = blockIdx.x;
  const int sp = bid & 3, j = (bid >> 2) & 15, b = bid >> 6;
  const int jB = 31 - j;
  const int nA = 2 * j + 2, nB = 64 - 2 * j;     // nA+nB == 66
  const bool sideA = (wid < 4);
  const int ws = sideA ? wid : wid - 4;
  const int tq0 = sideA ? j * 128 + 32 * ws : jB * 128 + 32 * ws;

  const char* kbase = (const char*)(kbm + (size_t)b * SEQ * HDIM);
  const char* vbase = (const char*)(vt  + (size_t)b * SEQ * HDIM);

  bf16x8 qf[4];
  {
    const unsigned short* qrow = qb + ((size_t)b * SEQ + tq0 + q5) * HDIM;
#pragma unroll
    for (int st = 0; st < 4; ++st)
      qf[st] = *(const bf16x8*)(qrow + 16 * st + 8 * h);
  }

  const int slot = tid * 16;
  const int r0 = slot >> 7, koff = r0 * 128 + ((slot & 127) ^ ((r0 & 7) << 4));

  float m = -1e30f, l = 0.f;
  f32x16 o0 = ZERO16, o1 = ZERO16;

  const int cnt = (66 - sp + NSPLIT - 1) / NSPLIT;   // 16 or 17

  bf16x8 rk0, rv0;
  // prologue: load item 0, write buf0, preload item 1
  {
    int kt; bool isA, diag;
    item_map128(sp, nA, nB, kt, isA, diag);
    rk0 = *(const bf16x8*)(kbase + (size_t)kt * 8192 + koff);
    rv0 = *(const bf16x8*)(vbase + (size_t)kt * 8192 + koff);
  }
  *(bf16x8*)((char*)sK[0] + slot) = rk0;
  *(bf16x8*)((char*)sV[0] + slot) = rv0;
  if (cnt > 1) {
    int kt; bool isA, diag;
    item_map128(sp + NSPLIT, nA, nB, kt, isA, diag);
    rk0 = *(const bf16x8*)(kbase + (size_t)kt * 8192 + koff);
    rv0 = *(const bf16x8*)(vbase + (size_t)kt * 8192 + koff);
  }
  __syncthreads();

  for (int ii = 0; ii < cnt; ++ii) {
    const int buf = ii & 1;
    if (ii + 1 < cnt) {                   // write item ii+1 into other buf
      const int nb = buf ^ 1;
      *(bf16x8*)((char*)sK[nb] + slot) = rk0;
      *(bf16x8*)((char*)sV[nb] + slot) = rv0;
    }
    if (ii + 2 < cnt) {                   // T14 issue-early: load item ii+2
      int kt; bool isA, diag;
      item_map128(sp + (ii + 2) * NSPLIT, nA, nB, kt, isA, diag);
      rk0 = *(const bf16x8*)(kbase + (size_t)kt * 8192 + koff);
      rv0 = *(const bf16x8*)(vbase + (size_t)kt * 8192 + koff);
    }
    int kt; bool isA, diag;
    item_map128(sp + ii * NSPLIT, nA, nB, kt, isA, diag);
    if (isA == sideA) {
      tile_body32(sK[buf], sV[buf], tq0 + q5 - kt * 64, diag, qf, h, q5,
                  m, l, o0, o1);
    }
    __syncthreads();                      // single barrier per item
  }

  l += __shfl_xor(l, 32);                 // both h-halves carry same l after
  l *= 0.5f;                              // in-body sums; avg == value (equal)

  // ---- write partial: lane owns query tq0+q5; dims split across h ----------
  const int grp = (sideA ? j * 8 + 2 * ws : jB * 8 + 2 * ws) + (q5 >> 4);
  float* pp = pw + ((size_t)(b * 256 + grp) * NSPLIT + sp) * 1056;
  const int qr = (q5 & 15) * 64;
#pragma unroll
  for (int quad = 0; quad < 4; ++quad) {
    *(f32x4*)(pp + qr + 8 * quad + 4 * h) =
        (f32x4){o0[4 * quad], o0[4 * quad + 1], o0[4 * quad + 2], o0[4 * quad + 3]};
    *(f32x4*)(pp + qr + 32 + 8 * quad + 4 * h) =
        (f32x4){o1[4 * quad], o1[4 * quad + 1], o1[4 * quad + 2], o1[4 * quad + 3]};
  }
  if (h == 0) { pp[1024 + (q5 & 15)] = m; pp[1040 + (q5 & 15)] = l; }
}

// ---- stage 2: merge NSPLIT partials per (batch, 16-query group), normalize -
__global__ __launch_bounds__(256) void attn_merge_kernel(
    const float* __restrict__ pw, float* __restrict__ out) {
  const int bid = blockIdx.x;                   // b*256 + grp
  const int b = bid >> 8, grp = bid & 255;
  const int q = threadIdx.x & 15, db = threadIdx.x >> 4;
  const float* pp = pw + (size_t)bid * NSPLIT * 1056;
  float ms[NSPLIT], ls[NSPLIT];
  float mm = -3e38f;
#pragma unroll
  for (int s = 0; s < NSPLIT; ++s) {
    ms[s] = pp[s * 1056 + 1024 + q];
    ls[s] = pp[s * 1056 + 1040 + q];
    mm = fmaxf(mm, ms[s]);
  }
  float L = 0.f, a0 = 0.f, a1 = 0.f, a2 = 0.f, a3 = 0.f;
#pragma unroll
  for (int s = 0; s < NSPLIT; ++s) {
    float sc = fexp2(ms[s] - mm);
    L += ls[s] * sc;
    float4 v = *(const float4*)(pp + s * 1056 + q * 64 + 4 * db);
    a0 += v.x * sc; a1 += v.y * sc; a2 += v.z * sc; a3 += v.w * sc;
  }
  const float inv = 1.f / L;
  float* op = out + ((size_t)b * SEQ + grp * 16 + q) * HDIM + 4 * db;
  op[0] = a0 * inv; op[1] = a1 * inv; op[2] = a2 * inv; op[3] = a3 * inv;
}

extern "C" void kernel_launch(void* const* d_in, const int* in_sizes, int n_in,
                              void* d_out, int out_size, void* d_ws, size_t ws_size,
                              hipStream_t stream) {
  const float* x  = (const float*)d_in[0];
  const float* Wq = (const float*)d_in[1];
  const float* Wk = (const float*)d_in[2];
  const float* Wv = (const float*)d_in[3];
  float* outp = (float*)d_out;

  const size_t rows = (size_t)BATCH * SEQ;        // 16384
  unsigned short* qbf = (unsigned short*)d_ws;
  unsigned short* kbf = qbf + rows * HDIM;
  unsigned short* vtb = kbf + rows * HDIM;
  unsigned short* wt  = vtb + rows * HDIM;        // 192*1024 bf16
  float* pw = (float*)(wt + 192 * 1024);          // 4096 partials x 1056 f32

  wt_kernel<<<dim3(48), dim3(256), 0, stream>>>(Wq, Wk, Wv, wt);
  qkv_mfma_kernel<<<dim3((unsigned)(rows / 64)), dim3(512), 0, stream>>>(x, wt, qbf, kbf, vtb);
  attn_partial_kernel<<<dim3(256), dim3(512), 0, stream>>>(qbf, kbf, vtb, pw);
  attn_merge_kernel<<<dim3(1024), dim3(256), 0, stream>>>(pw, outp);
}